// Round 3
// baseline (441.971 us; speedup 1.0000x reference)
//
#include <hip/hip_runtime.h>

// Overlaps: out[i,j] = IoU(boxes0[i], boxes1[j]) if (label,batch) match else 0
//
// R8 restructure: the output is 99.84% zeros (80 classes x 8 images = 640 keys,
// match prob 1/640). The runtime's own fillBufferAligned demonstrates 6.2 TB/s
// on this buffer; our fused kernel's write stream only achieved ~2.6 TB/s
// effective. So: split into
//   A) pure zero-fill kernel shaped exactly like the fast rocclr fill
//      (flat grid-stride, contiguous float4 stores, tiny register footprint)
//   B) sparse scan kernel: integer key compares only; wave-rows with zero
//      matches (67%) execute NO stores and NO float math; matched elements
//      (~156k of 1e8) get exec-masked scattered stores of IoU.
// Zero elements are never written by B (the fill already put 0 there).

typedef float fx4 __attribute__((ext_vector_type(4)));

// ---------------- Kernel A: zero-fill ----------------
__global__ __launch_bounds__(256) void zerofill_kernel(float4* __restrict__ out,
                                                       size_t count4)
{
    const size_t stride = (size_t)gridDim.x * blockDim.x;
    size_t i = (size_t)blockIdx.x * blockDim.x + threadIdx.x;
    const float4 z = make_float4(0.f, 0.f, 0.f, 0.f);
    for (; i < count4; i += stride)
        out[i] = z;
}

// ---------------- Kernel B: sparse scan ----------------
constexpr int ROWS_PER_BLOCK = 32;
constexpr int COLS_PER_BLOCK = 1024;  // 256 threads * 4 cols

__global__ __launch_bounds__(256) void scan_kernel(
    const float4* __restrict__ boxes0,   // [n0] xyxy
    const int*    __restrict__ labels0,  // [n0]
    const int*    __restrict__ batches0, // [n0]
    const float4* __restrict__ boxes1,   // [n1] xyxy
    const int*    __restrict__ labels1,  // [n1]
    const int*    __restrict__ batches1, // [n1]
    float*        __restrict__ out,      // [n0, n1], pre-zeroed by kernel A
    int n0, int n1)
{
    const int j4 = blockIdx.x * COLS_PER_BLOCK + threadIdx.x * 4;
    if (j4 >= n1) return;

    const int r0   = blockIdx.y * ROWS_PER_BLOCK;
    const int rend = (r0 + ROWS_PER_BLOCK < n0) ? (r0 + ROWS_PER_BLOCK) : n0;

    if (j4 + 3 < n1) {
        // column prologue: keys + boxes, loaded once, reused for all rows
        const int4 l1v = *reinterpret_cast<const int4*>(labels1 + j4);
        const int4 t1v = *reinterpret_cast<const int4*>(batches1 + j4);
        int k1[4];
        k1[0] = (t1v.x << 16) | (l1v.x & 0xFFFF);
        k1[1] = (t1v.y << 16) | (l1v.y & 0xFFFF);
        k1[2] = (t1v.z << 16) | (l1v.z & 0xFFFF);
        k1[3] = (t1v.w << 16) | (l1v.w & 0xFFFF);

        float4 b1[4];
        float  area1[4];
        #pragma unroll
        for (int k = 0; k < 4; ++k) {
            b1[k] = boxes1[j4 + k];
            area1[k] = (b1[k].z - b1[k].x) * (b1[k].w - b1[k].y);
        }

        for (int r = r0; r < rend; ++r) {
            // block-uniform -> scalar load
            const int k0 = (batches0[r] << 16) | (labels0[r] & 0xFFFF);

            bool m[4];
            #pragma unroll
            for (int k = 0; k < 4; ++k) m[k] = (k1[k] == k0);

            // 67% of wave-rows: no lane matches -> nothing to do at all
            if (!__any(m[0] || m[1] || m[2] || m[3])) continue;

            const float4 b0    = boxes0[r];
            const float  area0 = (b0.z - b0.x) * (b0.w - b0.y);
            float* orow = out + (size_t)r * n1 + j4;
            #pragma unroll
            for (int k = 0; k < 4; ++k) {
                if (m[k]) {
                    const float x1 = fmaxf(b0.x, b1[k].x);
                    const float y1 = fmaxf(b0.y, b1[k].y);
                    const float x2 = fminf(b0.z, b1[k].z);
                    const float y2 = fminf(b0.w, b1[k].w);
                    const float inter = fmaxf(x2 - x1, 0.0f) * fmaxf(y2 - y1, 0.0f);
                    const float uni = (area0 + area1[k]) - inter;
                    float v = inter * __builtin_amdgcn_rcpf(uni);
                    v = (uni > 0.0f) ? v : 0.0f;
                    orow[k] = v;
                }
            }
        }
    } else {
        // scalar tail (n1 not a multiple of 4)
        for (int r = r0; r < rend; ++r) {
            const float4 b0 = boxes0[r];
            const int    k0 = (batches0[r] << 16) | (labels0[r] & 0xFFFF);
            const float  area0 = (b0.z - b0.x) * (b0.w - b0.y);
            for (int j = j4; j < n1; ++j) {
                const int kj = (batches1[j] << 16) | (labels1[j] & 0xFFFF);
                if (kj != k0) continue;
                const float4 bb = boxes1[j];
                const float x1 = fmaxf(b0.x, bb.x);
                const float y1 = fmaxf(b0.y, bb.y);
                const float x2 = fminf(b0.z, bb.z);
                const float y2 = fminf(b0.w, bb.w);
                const float inter = fmaxf(x2 - x1, 0.0f) * fmaxf(y2 - y1, 0.0f);
                const float a1 = (bb.z - bb.x) * (bb.w - bb.y);
                const float uni = area0 + a1 - inter;
                out[(size_t)r * n1 + j] = (uni > 0.0f) ? (inter / uni) : 0.0f;
            }
        }
    }
}

extern "C" void kernel_launch(void* const* d_in, const int* in_sizes, int n_in,
                              void* d_out, int out_size, void* d_ws, size_t ws_size,
                              hipStream_t stream) {
    const float4* boxes0   = (const float4*)d_in[0];
    const int*    labels0  = (const int*)   d_in[1];
    const int*    batches0 = (const int*)   d_in[2];
    const float4* boxes1   = (const float4*)d_in[3];
    const int*    labels1  = (const int*)   d_in[4];
    const int*    batches1 = (const int*)   d_in[5];
    float*        out      = (float*)d_out;

    const int n0 = in_sizes[1];
    const int n1 = in_sizes[4];

    // ---- A: zero the whole output at fill speed ----
    const size_t total_bytes = (size_t)n0 * n1 * sizeof(float);
    const size_t count4 = total_bytes / sizeof(float4);  // n1=10000 -> divisible
    {
        const int fill_blocks = 4096;
        zerofill_kernel<<<fill_blocks, 256, 0, stream>>>((float4*)out, count4);
    }
    // handle any non-16B remainder (defensive; not hit for n1 % 4 == 0)
    // (n0*n1*4 % 16 != 0 only if n1 % 4 != 0; scan tail path rewrites those
    //  columns fully, including zeros)

    // ---- B: sparse scan, matched-only writes ----
    const int gx = (n1 + COLS_PER_BLOCK - 1) / COLS_PER_BLOCK;
    const int gy = (n0 + ROWS_PER_BLOCK - 1) / ROWS_PER_BLOCK;
    dim3 grid(gx, gy);
    scan_kernel<<<grid, 256, 0, stream>>>(
        boxes0, labels0, batches0, boxes1, labels1, batches1, out, n0, n1);
}

// Round 4
// 432.027 us; speedup vs baseline: 1.0230x; 1.0230x over previous
//
#include <hip/hip_runtime.h>

// Overlaps: out[i,j] = IoU(boxes0[i], boxes1[j]) if (label,batch) match else 0
//
// R9: output is 99.84% zeros (640 distinct (batch,label) keys -> P(match)=1/640).
// R8 showed our hand-written zero-fill runs at ~2.6-3 TB/s while the runtime's
// __amd_rocclr_fillBufferAligned sustains 6.2 TB/s on the same buffer class.
// So: delegate the zero-fill to hipMemsetAsync (routes to that fill kernel,
// graph-capture legal -- the harness's own reset() uses it), then run the
// sparse scan that writes ONLY the ~156k matched elements.

constexpr int ROWS_PER_BLOCK = 32;
constexpr int COLS_PER_BLOCK = 1024;  // 256 threads * 4 cols

__global__ __launch_bounds__(256) void scan_kernel(
    const float4* __restrict__ boxes0,   // [n0] xyxy
    const int*    __restrict__ labels0,  // [n0]
    const int*    __restrict__ batches0, // [n0]
    const float4* __restrict__ boxes1,   // [n1] xyxy
    const int*    __restrict__ labels1,  // [n1]
    const int*    __restrict__ batches1, // [n1]
    float*        __restrict__ out,      // [n0, n1], pre-zeroed by memset
    int n0, int n1)
{
    const int j4 = blockIdx.x * COLS_PER_BLOCK + threadIdx.x * 4;
    if (j4 >= n1) return;

    const int r0   = blockIdx.y * ROWS_PER_BLOCK;
    const int rend = (r0 + ROWS_PER_BLOCK < n0) ? (r0 + ROWS_PER_BLOCK) : n0;

    if (j4 + 3 < n1) {
        // column prologue: keys + boxes, loaded once, reused for all rows
        const int4 l1v = *reinterpret_cast<const int4*>(labels1 + j4);
        const int4 t1v = *reinterpret_cast<const int4*>(batches1 + j4);
        int k1[4];
        k1[0] = (t1v.x << 16) | (l1v.x & 0xFFFF);
        k1[1] = (t1v.y << 16) | (l1v.y & 0xFFFF);
        k1[2] = (t1v.z << 16) | (l1v.z & 0xFFFF);
        k1[3] = (t1v.w << 16) | (l1v.w & 0xFFFF);

        float4 b1[4];
        float  area1[4];
        #pragma unroll
        for (int k = 0; k < 4; ++k) {
            b1[k] = boxes1[j4 + k];
            area1[k] = (b1[k].z - b1[k].x) * (b1[k].w - b1[k].y);
        }

        for (int r = r0; r < rend; ++r) {
            // block-uniform -> scalar load
            const int k0 = (batches0[r] << 16) | (labels0[r] & 0xFFFF);

            bool m[4];
            #pragma unroll
            for (int k = 0; k < 4; ++k) m[k] = (k1[k] == k0);

            // 67% of wave-rows: no lane matches -> nothing to do at all
            if (!__any(m[0] || m[1] || m[2] || m[3])) continue;

            const float4 b0    = boxes0[r];
            const float  area0 = (b0.z - b0.x) * (b0.w - b0.y);
            float* orow = out + (size_t)r * n1 + j4;
            #pragma unroll
            for (int k = 0; k < 4; ++k) {
                if (m[k]) {
                    const float x1 = fmaxf(b0.x, b1[k].x);
                    const float y1 = fmaxf(b0.y, b1[k].y);
                    const float x2 = fminf(b0.z, b1[k].z);
                    const float y2 = fminf(b0.w, b1[k].w);
                    const float inter = fmaxf(x2 - x1, 0.0f) * fmaxf(y2 - y1, 0.0f);
                    const float uni = (area0 + area1[k]) - inter;
                    float v = inter * __builtin_amdgcn_rcpf(uni);
                    v = (uni > 0.0f) ? v : 0.0f;
                    orow[k] = v;
                }
            }
        }
    } else {
        // scalar tail (n1 not a multiple of 4)
        for (int r = r0; r < rend; ++r) {
            const float4 b0 = boxes0[r];
            const int    k0 = (batches0[r] << 16) | (labels0[r] & 0xFFFF);
            const float  area0 = (b0.z - b0.x) * (b0.w - b0.y);
            for (int j = j4; j < n1; ++j) {
                const int kj = (batches1[j] << 16) | (labels1[j] & 0xFFFF);
                if (kj != k0) continue;
                const float4 bb = boxes1[j];
                const float x1 = fmaxf(b0.x, bb.x);
                const float y1 = fmaxf(b0.y, bb.y);
                const float x2 = fminf(b0.z, bb.z);
                const float y2 = fminf(b0.w, bb.w);
                const float inter = fmaxf(x2 - x1, 0.0f) * fmaxf(y2 - y1, 0.0f);
                const float a1 = (bb.z - bb.x) * (bb.w - bb.y);
                const float uni = area0 + a1 - inter;
                out[(size_t)r * n1 + j] = (uni > 0.0f) ? (inter / uni) : 0.0f;
            }
        }
    }
}

extern "C" void kernel_launch(void* const* d_in, const int* in_sizes, int n_in,
                              void* d_out, int out_size, void* d_ws, size_t ws_size,
                              hipStream_t stream) {
    const float4* boxes0   = (const float4*)d_in[0];
    const int*    labels0  = (const int*)   d_in[1];
    const int*    batches0 = (const int*)   d_in[2];
    const float4* boxes1   = (const float4*)d_in[3];
    const int*    labels1  = (const int*)   d_in[4];
    const int*    batches1 = (const int*)   d_in[5];
    float*        out      = (float*)d_out;

    const int n0 = in_sizes[1];
    const int n1 = in_sizes[4];

    // ---- A: zero the output via the runtime's fill path (6.2 TB/s measured) ----
    hipMemsetAsync(d_out, 0, (size_t)n0 * (size_t)n1 * sizeof(float), stream);

    // ---- B: sparse scan, matched-only writes ----
    const int gx = (n1 + COLS_PER_BLOCK - 1) / COLS_PER_BLOCK;
    const int gy = (n0 + ROWS_PER_BLOCK - 1) / ROWS_PER_BLOCK;
    dim3 grid(gx, gy);
    scan_kernel<<<grid, 256, 0, stream>>>(
        boxes0, labels0, batches0, boxes1, labels1, batches1, out, n0, n1);
}

// Round 5
// 415.623 us; speedup vs baseline: 1.0634x; 1.0395x over previous
//
#include <hip/hip_runtime.h>

// Overlaps: out[i,j] = IoU(boxes0[i], boxes1[j]) if (label,batch) match else 0
//
// R10: one block per output ROW, threads sweep the row linearly.
//  - Store stream is globally linear (block b writes row b contiguously,
//    consecutive blocks = consecutive 40KB rows) == the access pattern of
//    __amd_rocclr_fillBufferAligned, which demonstrates 6.2 TB/s on this
//    buffer. Prior 2D-grid kernels (8-32 scattered row-segments per block)
//    never exceeded ~2.9 TB/s effective; this isolates write-order as the
//    suspected binder.
//  - Row key/box are block-uniform (scalar regs), loaded once per block.
//  - Sparsity: 640 distinct keys -> P(match)=1/640; per 256-col wave window
//    P(no match) ~ 67% -> wave-vote skips all float math, stores zeros.
//  - Column keys re-read per block from L1/L2 (80 KB/block, L2-resident;
//    ~23 us aggregate at L2 rate, hidden under the store stream).

constexpr int TPB = 256;

__global__ __launch_bounds__(256) void overlaps_row_kernel(
    const float4* __restrict__ boxes0,   // [n0] xyxy
    const int*    __restrict__ labels0,  // [n0]
    const int*    __restrict__ batches0, // [n0]
    const float4* __restrict__ boxes1,   // [n1] xyxy
    const int*    __restrict__ labels1,  // [n1]
    const int*    __restrict__ batches1, // [n1]
    float*        __restrict__ out,      // [n0, n1]
    int n0, int n1)
{
    const int r = blockIdx.x;
    if (r >= n0) return;

    // block-uniform row data
    const int    k0    = (batches0[r] << 16) | (labels0[r] & 0xFFFF);
    const float4 b0    = boxes0[r];
    const float  area0 = (b0.z - b0.x) * (b0.w - b0.y);
    float* orow = out + (size_t)r * n1;

    const int nq = n1 >> 2;  // full quads in the row

    for (int q = threadIdx.x; q < nq; q += TPB) {
        const int j4 = q << 2;   // j4 % 4 == 0 -> int4/float4 aligned

        const int4 l1v = *reinterpret_cast<const int4*>(labels1 + j4);
        const int4 t1v = *reinterpret_cast<const int4*>(batches1 + j4);
        int k1[4];
        k1[0] = (t1v.x << 16) | (l1v.x & 0xFFFF);
        k1[1] = (t1v.y << 16) | (l1v.y & 0xFFFF);
        k1[2] = (t1v.z << 16) | (l1v.z & 0xFFFF);
        k1[3] = (t1v.w << 16) | (l1v.w & 0xFFFF);

        bool m[4];
        #pragma unroll
        for (int k = 0; k < 4; ++k) m[k] = (k1[k] == k0);

        float4 res = make_float4(0.f, 0.f, 0.f, 0.f);
        float* rp = &res.x;

        // 67% of wave-windows: no lane matches -> store zeros, no float math
        if (__any(m[0] || m[1] || m[2] || m[3])) {
            #pragma unroll
            for (int k = 0; k < 4; ++k) {
                if (m[k]) {
                    const float4 bb = boxes1[j4 + k];
                    const float x1 = fmaxf(b0.x, bb.x);
                    const float y1 = fmaxf(b0.y, bb.y);
                    const float x2 = fminf(b0.z, bb.z);
                    const float y2 = fminf(b0.w, bb.w);
                    const float inter = fmaxf(x2 - x1, 0.0f) * fmaxf(y2 - y1, 0.0f);
                    const float a1  = (bb.z - bb.x) * (bb.w - bb.y);
                    const float uni = (area0 + a1) - inter;
                    float v = inter * __builtin_amdgcn_rcpf(uni);
                    rp[k] = (uni > 0.0f) ? v : 0.0f;
                }
            }
        }

        *reinterpret_cast<float4*>(orow + j4) = res;
    }

    // tail (n1 % 4 != 0)
    for (int j = (nq << 2) + threadIdx.x; j < n1; j += TPB) {
        float v = 0.0f;
        const int kj = (batches1[j] << 16) | (labels1[j] & 0xFFFF);
        if (kj == k0) {
            const float4 bb = boxes1[j];
            const float x1 = fmaxf(b0.x, bb.x);
            const float y1 = fmaxf(b0.y, bb.y);
            const float x2 = fminf(b0.z, bb.z);
            const float y2 = fminf(b0.w, bb.w);
            const float inter = fmaxf(x2 - x1, 0.0f) * fmaxf(y2 - y1, 0.0f);
            const float a1  = (bb.z - bb.x) * (bb.w - bb.y);
            const float uni = (area0 + a1) - inter;
            v = (uni > 0.0f) ? (inter / uni) : 0.0f;
        }
        orow[j] = v;
    }
}

extern "C" void kernel_launch(void* const* d_in, const int* in_sizes, int n_in,
                              void* d_out, int out_size, void* d_ws, size_t ws_size,
                              hipStream_t stream) {
    const float4* boxes0   = (const float4*)d_in[0];
    const int*    labels0  = (const int*)   d_in[1];
    const int*    batches0 = (const int*)   d_in[2];
    const float4* boxes1   = (const float4*)d_in[3];
    const int*    labels1  = (const int*)   d_in[4];
    const int*    batches1 = (const int*)   d_in[5];
    float*        out      = (float*)d_out;

    const int n0 = in_sizes[1];
    const int n1 = in_sizes[4];

    overlaps_row_kernel<<<dim3(n0), TPB, 0, stream>>>(
        boxes0, labels0, batches0, boxes1, labels1, batches1, out, n0, n1);
}

// Round 6
// 403.875 us; speedup vs baseline: 1.0943x; 1.0291x over previous
//
#include <hip/hip_runtime.h>

// Overlaps: out[i,j] = IoU(boxes0[i], boxes1[j]) if (label,batch) match else 0
//
// R11 = restore R7 (best measured: 405.5 us total). Session decomposition,
// counter-evidenced across R7-R10:
//   - harness poison fill: 1.6 GB @ 6.2 TB/s ~ 258 us (visible in rocprof,
//     outside kernel control)
//   - fixed harness overhead ~75-85 us: proven by R9, where 400 MB was
//     written by the runtime's own >=6.2 TB/s fill (<=65 us) plus a <=20 us
//     sparse scan, yet the non-poison portion was still 162 us.
//   - this kernel: mandatory 400 MB write; ~75-80 us (~5+ TB/s effective)
//     vs 65 us floor at the fill-demonstrated rate.
// Floor ~ 398 us total; R7 measured 405. Structural variants tried and
// rejected: row-linear store order (R10, -0), fill+scan split (R8, -20),
// memset+scan (R9, -15). Write-order does NOT explain the fill-vs-kernel
// BW gap; per-dispatch fixed overhead does.
//
// Structure: 8 rows x 1024 cols per block, wave-vote sparsity early-out
// (640 keys -> 67% of wave-rows all-zero), nontemporal float4 stores.

typedef float fx4 __attribute__((ext_vector_type(4)));

constexpr int ROWS_PER_BLOCK = 8;
constexpr int COLS_PER_BLOCK = 1024;  // 256 threads * 4 cols

__global__ __launch_bounds__(256) void overlaps_kernel(
    const float4* __restrict__ boxes0,   // [n0] xyxy
    const int*    __restrict__ labels0,  // [n0]
    const int*    __restrict__ batches0, // [n0]
    const float4* __restrict__ boxes1,   // [n1] xyxy
    const int*    __restrict__ labels1,  // [n1]
    const int*    __restrict__ batches1, // [n1]
    float*        __restrict__ out,      // [n0, n1]
    int n0, int n1)
{
    const int j4 = blockIdx.x * COLS_PER_BLOCK + threadIdx.x * 4;
    if (j4 >= n1) return;

    const int r0   = blockIdx.y * ROWS_PER_BLOCK;
    const int rend = (r0 + ROWS_PER_BLOCK < n0) ? (r0 + ROWS_PER_BLOCK) : n0;

    if (j4 + 3 < n1) {
        // ---- column prologue: loaded once, reused for all rows ----
        const int4 l1v = *reinterpret_cast<const int4*>(labels1 + j4);
        const int4 t1v = *reinterpret_cast<const int4*>(batches1 + j4);
        int k1[4];
        k1[0] = (t1v.x << 16) | (l1v.x & 0xFFFF);
        k1[1] = (t1v.y << 16) | (l1v.y & 0xFFFF);
        k1[2] = (t1v.z << 16) | (l1v.z & 0xFFFF);
        k1[3] = (t1v.w << 16) | (l1v.w & 0xFFFF);

        float4 b1[4];
        float  area1[4];
        #pragma unroll
        for (int k = 0; k < 4; ++k) {
            b1[k] = boxes1[j4 + k];
            area1[k] = (b1[k].z - b1[k].x) * (b1[k].w - b1[k].y);
        }

        float* orow = out + (size_t)r0 * n1 + j4;

        #pragma unroll 4
        for (int r = r0; r < rend; ++r) {
            // block-uniform -> scalar loads
            const int k0 = (batches0[r] << 16) | (labels0[r] & 0xFFFF);

            bool m[4];
            #pragma unroll
            for (int k = 0; k < 4; ++k) m[k] = (k1[k] == k0);

            fx4 res = (fx4)(0.0f);

            // wave-uniform vote: 67% of wave-rows have zero matches across all
            // 64 lanes x 4 cols -> skip the entire IoU float pipeline.
            if (__any(m[0] || m[1] || m[2] || m[3])) {
                const float4 b0    = boxes0[r];
                const float  area0 = (b0.z - b0.x) * (b0.w - b0.y);
                #pragma unroll
                for (int k = 0; k < 4; ++k) {
                    const float x1 = fmaxf(b0.x, b1[k].x);
                    const float y1 = fmaxf(b0.y, b1[k].y);
                    const float x2 = fminf(b0.z, b1[k].z);
                    const float y2 = fminf(b0.w, b1[k].w);
                    const float inter = fmaxf(x2 - x1, 0.0f) * fmaxf(y2 - y1, 0.0f);
                    const float uni = (area0 + area1[k]) - inter;
                    float v = inter * __builtin_amdgcn_rcpf(uni);
                    v = (uni > 0.0f) ? v : 0.0f;
                    res[k] = m[k] ? v : 0.0f;
                }
            }

            __builtin_nontemporal_store(res, reinterpret_cast<fx4*>(orow));
            orow += n1;
        }
    } else {
        // scalar tail (n1 not a multiple of 4)
        for (int r = r0; r < rend; ++r) {
            const float4 b0 = boxes0[r];
            const int    k0 = (batches0[r] << 16) | (labels0[r] & 0xFFFF);
            const float  area0 = (b0.z - b0.x) * (b0.w - b0.y);
            for (int j = j4; j < n1; ++j) {
                float v = 0.0f;
                const int kj = (batches1[j] << 16) | (labels1[j] & 0xFFFF);
                if (kj == k0) {
                    const float4 bb = boxes1[j];
                    const float x1 = fmaxf(b0.x, bb.x);
                    const float y1 = fmaxf(b0.y, bb.y);
                    const float x2 = fminf(b0.z, bb.z);
                    const float y2 = fminf(b0.w, bb.w);
                    const float inter = fmaxf(x2 - x1, 0.0f) * fmaxf(y2 - y1, 0.0f);
                    const float a1 = (bb.z - bb.x) * (bb.w - bb.y);
                    const float uni = area0 + a1 - inter;
                    v = (uni > 0.0f) ? (inter / uni) : 0.0f;
                }
                out[(size_t)r * n1 + j] = v;
            }
        }
    }
}

extern "C" void kernel_launch(void* const* d_in, const int* in_sizes, int n_in,
                              void* d_out, int out_size, void* d_ws, size_t ws_size,
                              hipStream_t stream) {
    const float4* boxes0   = (const float4*)d_in[0];
    const int*    labels0  = (const int*)   d_in[1];
    const int*    batches0 = (const int*)   d_in[2];
    const float4* boxes1   = (const float4*)d_in[3];
    const int*    labels1  = (const int*)   d_in[4];
    const int*    batches1 = (const int*)   d_in[5];
    float*        out      = (float*)d_out;

    const int n0 = in_sizes[1];
    const int n1 = in_sizes[4];

    const int gx = (n1 + COLS_PER_BLOCK - 1) / COLS_PER_BLOCK;
    const int gy = (n0 + ROWS_PER_BLOCK - 1) / ROWS_PER_BLOCK;
    dim3 grid(gx, gy);

    overlaps_kernel<<<grid, 256, 0, stream>>>(
        boxes0, labels0, batches0, boxes1, labels1, batches1, out, n0, n1);
}